// Round 2
// baseline (36057.919 us; speedup 1.0000x reference)
//
#include <hip/hip_runtime.h>
#include <hip/hip_cooperative_groups.h>

namespace cg = cooperative_groups;

// Problem constants
#define Bn   64
#define Tn   512
#define Dn   256
#define Un   512
#define Mn   64
#define NCOL 2112                 // 4U + M
#define ABLK 132                  // 33 col-tiles(64) x 4 b-tiles(16)
#define NTHR 512
#define CHIST_FLOATS (Bn * Mn * Un)   // 2097152
#define Z_FLOATS     (Bn * NCOL)      // 135168

// ws layout: z [Bn*NCOL] | chist [Bn*64*Un] (circular c-history) | hbuf [Bn*Un]
// total ~9.1 MB

__device__ __forceinline__ float sigmoidf_(float v) { return 1.0f / (1.0f + __expf(-v)); }

// Per-wg / per-thread phase-A config. col-tile = 64 cols (so each tile sits in
// exactly one weight segment: tiles 0..31 = gates i,f,o,c; tile 32 = e).
__device__ __forceinline__ void cfgA(int wg, int tid,
    const float* Wi, const float* Ui, const float* bi,
    const float* Wf, const float* Uf, const float* bf_,
    const float* Wo, const float* Uo, const float* bo,
    const float* Wc, const float* Uc, const float* bc,
    const float* We, const float* Ue, const float* be,
    const float*& wp, const float*& up, int& ld, float& bias, int& b0, int& n)
{
    const int ct = wg % 33, bt = wg / 33;
    b0 = bt << 4;
    n  = (ct << 6) + (tid & 63);
    const int seg = n >> 9;                       // 0..3 gates, 4 = e
    const float *Wt, *Ut, *Bt;
    if      (seg == 0) { Wt = Wi; Ut = Ui; Bt = bi;  }
    else if (seg == 1) { Wt = Wf; Ut = Uf; Bt = bf_; }
    else if (seg == 2) { Wt = Wo; Ut = Uo; Bt = bo;  }
    else if (seg == 3) { Wt = Wc; Ut = Uc; Bt = bc;  }
    else               { Wt = We; Ut = Ue; Bt = be;  }
    ld = (seg < 4) ? Un : Mn;
    const int cs = n - (seg << 9);
    wp = Wt + cs; up = Ut + cs; bias = Bt[cs];
}

// Phase A: z[b0:b0+16, n-tile] = [x_t | h] @ [W; U] + b.  smem = 48 KB xh tile.
__device__ __forceinline__ void phaseA_body(
    int t, int tid, float* smem,
    const float* __restrict__ x, const float* __restrict__ hbuf,
    float* __restrict__ z,
    const float* __restrict__ wp_base, const float* __restrict__ up_base,
    int ld, float bias, int b0, int n)
{
    float* sx = smem;           // [16][256]
    float* sh = smem + 4096;    // [16][512]
    {
        const float4* xg = (const float4*)x;
        float4* sx4 = (float4*)sx;
        for (int i = tid; i < 16 * 64; i += NTHR) {            // 2 iters
            const int r = i >> 6, c4 = i & 63;
            sx4[i] = xg[((b0 + r) * Tn + t) * 64 + c4];        // x[b][t][:]
        }
        const float4* hg = (const float4*)hbuf;
        float4* sh4 = (float4*)sh;
        for (int i = tid; i < 16 * 128; i += NTHR) {           // 4 iters
            const int r = i >> 7;
            sh4[i] = hg[((b0 + r) << 7) + (i & 127)];          // h[b][:]
        }
    }
    __syncthreads();

    const int rg  = tid >> 6;                                  // 8 row-pairs
    const int ld2 = ld + ld, ld3 = ld2 + ld, ld4 = ld2 + ld2;
    float acc0 = bias, acc1 = bias;
    {   // x @ W, k = 0..255
        const float* wp = wp_base;
        const float4* a0 = (const float4*)(sx + (rg << 1) * 256);
        const float4* a1 = a0 + 64;
        #pragma unroll 8
        for (int kk = 0; kk < 64; ++kk) {
            const float w0 = wp[0], w1 = wp[ld], w2 = wp[ld2], w3 = wp[ld3];
            wp += ld4;
            const float4 v0 = a0[kk], v1 = a1[kk];
            acc0 = fmaf(w0, v0.x, acc0); acc1 = fmaf(w0, v1.x, acc1);
            acc0 = fmaf(w1, v0.y, acc0); acc1 = fmaf(w1, v1.y, acc1);
            acc0 = fmaf(w2, v0.z, acc0); acc1 = fmaf(w2, v1.z, acc1);
            acc0 = fmaf(w3, v0.w, acc0); acc1 = fmaf(w3, v1.w, acc1);
        }
    }
    {   // h @ U, k = 0..511
        const float* up = up_base;
        const float4* a0 = (const float4*)(sh + (rg << 1) * 512);
        const float4* a1 = a0 + 128;
        #pragma unroll 8
        for (int kk = 0; kk < 128; ++kk) {
            const float w0 = up[0], w1 = up[ld], w2 = up[ld2], w3 = up[ld3];
            up += ld4;
            const float4 v0 = a0[kk], v1 = a1[kk];
            acc0 = fmaf(w0, v0.x, acc0); acc1 = fmaf(w0, v1.x, acc1);
            acc0 = fmaf(w1, v0.y, acc0); acc1 = fmaf(w1, v1.y, acc1);
            acc0 = fmaf(w2, v0.z, acc0); acc1 = fmaf(w2, v1.z, acc1);
            acc0 = fmaf(w3, v0.w, acc0); acc1 = fmaf(w3, v1.w, acc1);
        }
    }
    const int row = b0 + (rg << 1);
    z[row * NCOL + n]       = acc0;
    z[(row + 1) * NCOL + n] = acc1;
}

// Phase B for batch b: e = softmax(ze); c = f*(e . mem) + i*c~; h = o*tanh(c).
// chist[b][slot][u] circular: slot for c_s is s & 63; zero slots = t<64 zeros.
__device__ __forceinline__ void phaseB_body(
    int t, int b, int tid, float* esm,
    const float* __restrict__ z, float* __restrict__ chist,
    float* __restrict__ hbuf, float* __restrict__ out)
{
    if (tid < 64) {
        const float v = z[b * NCOL + 2048 + tid];
        float m = v;
        #pragma unroll
        for (int off = 32; off; off >>= 1) m = fmaxf(m, __shfl_xor(m, off, 64));
        const float ex = __expf(v - m);
        float s = ex;
        #pragma unroll
        for (int off = 32; off; off >>= 1) s += __shfl_xor(s, off, 64);
        esm[tid] = ex / s;
    }
    __syncthreads();
    const int u = tid;
    const float* zb = z + b * NCOL;
    const float zi = zb[u], zf = zb[Un + u], zo = zb[2 * Un + u], zc = zb[3 * Un + u];
    float* ch = chist + ((b << 6) << 9) + u;
    float mc = 0.0f;
    #pragma unroll 8
    for (int j = 0; j < 64; ++j) {
        const int slot = (t + 63 - j) & 63;        // (t-1-j) mod 64
        mc = fmaf(esm[j], ch[slot << 9], mc);
    }
    const float ig  = sigmoidf_(zi);
    const float fg  = sigmoidf_(zf);
    const float og  = sigmoidf_(zo);
    const float ctl = tanhf(zc);
    const float cc  = fg * mc + ig * ctl;
    const float hh  = og * tanhf(cc);
    ch[(t & 63) << 9]            = cc;             // newest c -> slot t%64
    hbuf[(b << 9) + u]           = hh;
    out[((b * Tn + t) << 9) + u] = hh;
}

// ---------------- cooperative single-launch path ----------------
__global__ __launch_bounds__(NTHR) void xlstm_coop(
    const float* __restrict__ x,
    const float* __restrict__ Wi, const float* __restrict__ Ui, const float* __restrict__ bi,
    const float* __restrict__ Wf, const float* __restrict__ Uf, const float* __restrict__ bf_,
    const float* __restrict__ Wo, const float* __restrict__ Uo, const float* __restrict__ bo,
    const float* __restrict__ Wc, const float* __restrict__ Uc, const float* __restrict__ bc,
    const float* __restrict__ We, const float* __restrict__ Ue, const float* __restrict__ be,
    float* __restrict__ out, float* __restrict__ ws)
{
    cg::grid_group grid = cg::this_grid();
    __shared__ float smem[12288];   // 48 KB
    float* z     = ws;
    float* chist = ws + Z_FLOATS;
    float* hbuf  = chist + CHIST_FLOATS;

    const int tid = threadIdx.x, wg = blockIdx.x;

    for (int i = wg * NTHR + tid; i < CHIST_FLOATS + Bn * Un; i += ABLK * NTHR)
        chist[i] = 0.0f;            // zero chist + hbuf (ws is poisoned 0xAA)
    grid.sync();

    const float *wp, *up; int ld, b0, n; float bias;
    cfgA(wg, tid, Wi, Ui, bi, Wf, Uf, bf_, Wo, Uo, bo, Wc, Uc, bc, We, Ue, be,
         wp, up, ld, bias, b0, n);

    for (int t = 0; t < Tn; ++t) {
        phaseA_body(t, tid, smem, x, hbuf, z, wp, up, ld, bias, b0, n);
        grid.sync();
        if (wg < Bn) phaseB_body(t, wg, tid, smem, z, chist, hbuf, out);
        grid.sync();
    }
}

// ---------------- fallback multi-launch path ----------------
__global__ __launch_bounds__(NTHR) void init_k(float* __restrict__ ws)
{
    float* chist = ws + Z_FLOATS;
    for (int i = blockIdx.x * NTHR + threadIdx.x; i < CHIST_FLOATS + Bn * Un;
         i += gridDim.x * NTHR)
        chist[i] = 0.0f;
}

__global__ __launch_bounds__(NTHR) void stepA_k(
    int t, const float* __restrict__ x,
    const float* __restrict__ Wi, const float* __restrict__ Ui, const float* __restrict__ bi,
    const float* __restrict__ Wf, const float* __restrict__ Uf, const float* __restrict__ bf_,
    const float* __restrict__ Wo, const float* __restrict__ Uo, const float* __restrict__ bo,
    const float* __restrict__ Wc, const float* __restrict__ Uc, const float* __restrict__ bc,
    const float* __restrict__ We, const float* __restrict__ Ue, const float* __restrict__ be,
    float* __restrict__ ws)
{
    __shared__ float smem[12288];
    float* z     = ws;
    float* chist = ws + Z_FLOATS;
    float* hbuf  = chist + CHIST_FLOATS;
    const float *wp, *up; int ld, b0, n; float bias;
    cfgA(blockIdx.x, threadIdx.x, Wi, Ui, bi, Wf, Uf, bf_, Wo, Uo, bo,
         Wc, Uc, bc, We, Ue, be, wp, up, ld, bias, b0, n);
    phaseA_body(t, threadIdx.x, smem, x, hbuf, z, wp, up, ld, bias, b0, n);
}

__global__ __launch_bounds__(NTHR) void stepB_k(
    int t, float* __restrict__ out, float* __restrict__ ws)
{
    __shared__ float esm[64];
    float* z     = ws;
    float* chist = ws + Z_FLOATS;
    float* hbuf  = chist + CHIST_FLOATS;
    phaseB_body(t, blockIdx.x, threadIdx.x, esm, z, chist, hbuf, out);
}

extern "C" void kernel_launch(void* const* d_in, const int* in_sizes, int n_in,
                              void* d_out, int out_size, void* d_ws, size_t ws_size,
                              hipStream_t stream) {
    const float* x  = (const float*)d_in[0];
    const float* Wi = (const float*)d_in[1];
    const float* Ui = (const float*)d_in[2];
    const float* bi = (const float*)d_in[3];
    const float* Wf = (const float*)d_in[4];
    const float* Uf = (const float*)d_in[5];
    const float* bf = (const float*)d_in[6];
    const float* Wo = (const float*)d_in[7];
    const float* Uo = (const float*)d_in[8];
    const float* bo = (const float*)d_in[9];
    const float* Wc = (const float*)d_in[10];
    const float* Uc = (const float*)d_in[11];
    const float* bc = (const float*)d_in[12];
    const float* We = (const float*)d_in[13];
    const float* Ue = (const float*)d_in[14];
    const float* be = (const float*)d_in[15];
    float* out = (float*)d_out;
    float* ws  = (float*)d_ws;

    void* args[] = { &x, &Wi, &Ui, &bi, &Wf, &Uf, &bf, &Wo, &Uo, &bo,
                     &Wc, &Uc, &bc, &We, &Ue, &be, &out, &ws };
    hipError_t e = hipLaunchCooperativeKernel((const void*)xlstm_coop,
                                              dim3(ABLK), dim3(NTHR), args, 0, stream);
    if (e != hipSuccess) {
        (void)hipGetLastError();   // clear sticky error; use per-step fallback
        init_k<<<256, NTHR, 0, stream>>>(ws);
        for (int t = 0; t < Tn; ++t) {
            stepA_k<<<ABLK, NTHR, 0, stream>>>(t, x, Wi, Ui, bi, Wf, Uf, bf,
                                               Wo, Uo, bo, Wc, Uc, bc, We, Ue, be, ws);
            stepB_k<<<Bn, NTHR, 0, stream>>>(t, out, ws);
        }
    }
}

// Round 3
// 29152.975 us; speedup vs baseline: 1.2369x; 1.2369x over previous
//
#include <hip/hip_runtime.h>

// Problem constants
#define Bn   64
#define Tn   512
#define Dn   256
#define Un   512
#define Mn   64
#define NCOL 2112                 // 4U + M
#define ABLK 132                  // 33 col-tiles(64) x 4 b-tiles(16)
#define NTHR 512
#define CHIST_FLOATS (Bn * Mn * Un)   // 2097152
#define Z_FLOATS     (Bn * NCOL)      // 135168
#define CTR_PAD 64                    // floats reserved at ws[0] for the barrier counter

// ws layout: ctr[64] | z [Bn*NCOL] | chist [Bn*64*Un] | hbuf [Bn*Un]   (~9.1 MB)
//
// Coherence design (the R3 change): NO cg::grid.sync() — its acquire fence
// (buffer_inv) evicted the 6.5 MB read-only weight set from every L2 each of
// the 1024 syncs (R2: FETCH_SIZE = 11.6 MB/step). Instead:
//   - weights / x / chist / out: normal loads & stores (L1/L2-cached; chist is
//     wg-private, weights read-only -> stay L2-resident all 512 steps)
//   - cross-wg data (z, hbuf) + barrier counter: agent-scope relaxed atomics
//     (bypass non-coherent per-XCD L2, visible at retire; m20-verified path)
//   - barrier: per-wave s_waitcnt(0) drain -> __syncthreads -> one atomic add
//     + spin on a monotonic counter. No acquire/release fences anywhere.

__device__ __forceinline__ float sigmoidf_(float v) { return 1.0f / (1.0f + __expf(-v)); }

__device__ __forceinline__ void st_agent_f32(float* p, float v) {
    __hip_atomic_store(p, v, __ATOMIC_RELAXED, __HIP_MEMORY_SCOPE_AGENT);
}
__device__ __forceinline__ float ld_agent_f32(const float* p) {
    return __hip_atomic_load(p, __ATOMIC_RELAXED, __HIP_MEMORY_SCOPE_AGENT);
}
__device__ __forceinline__ unsigned long long ld_agent_u64(const void* p) {
    return __hip_atomic_load((const unsigned long long*)p, __ATOMIC_RELAXED,
                             __HIP_MEMORY_SCOPE_AGENT);
}

// Grid barrier: all ABLK wgs arrive (monotonic target), none releases early.
__device__ __forceinline__ void gbar(unsigned* ctr, unsigned target) {
    __builtin_amdgcn_s_waitcnt(0);     // drain THIS wave's agent stores (visible at retire)
    __syncthreads();                   // all waves of the wg drained & arrived
    if (threadIdx.x == 0) {
        __hip_atomic_fetch_add(ctr, 1u, __ATOMIC_RELAXED, __HIP_MEMORY_SCOPE_AGENT);
        while (__hip_atomic_load(ctr, __ATOMIC_RELAXED, __HIP_MEMORY_SCOPE_AGENT) < target)
            __builtin_amdgcn_s_sleep(1);
    }
    __syncthreads();
}

// Per-wg / per-thread phase-A config. col-tile = 64 cols (tile sits in exactly
// one weight segment: tiles 0..31 = gates i,f,o,c; tile 32 = e).
__device__ __forceinline__ void cfgA(int wg, int tid,
    const float* Wi, const float* Ui, const float* bi,
    const float* Wf, const float* Uf, const float* bf_,
    const float* Wo, const float* Uo, const float* bo,
    const float* Wc, const float* Uc, const float* bc,
    const float* We, const float* Ue, const float* be,
    const float*& wp, const float*& up, int& ld, float& bias, int& b0, int& n)
{
    const int ct = wg % 33, bt = wg / 33;
    b0 = bt << 4;
    n  = (ct << 6) + (tid & 63);
    const int seg = n >> 9;                       // 0..3 gates, 4 = e
    const float *Wt, *Ut, *Bt;
    if      (seg == 0) { Wt = Wi; Ut = Ui; Bt = bi;  }
    else if (seg == 1) { Wt = Wf; Ut = Uf; Bt = bf_; }
    else if (seg == 2) { Wt = Wo; Ut = Uo; Bt = bo;  }
    else if (seg == 3) { Wt = Wc; Ut = Uc; Bt = bc;  }
    else               { Wt = We; Ut = Ue; Bt = be;  }
    ld = (seg < 4) ? Un : Mn;
    const int cs = n - (seg << 9);
    wp = Wt + cs; up = Ut + cs; bias = Bt[cs];
}

// Phase A: z[b0:b0+16, n-tile] = [x_t | h] @ [W; U] + b.  smem = 48 KB xh tile.
__device__ __forceinline__ void phaseA_body(
    int t, int tid, float* smem,
    const float* __restrict__ x, const float* __restrict__ hbuf,
    float* __restrict__ z,
    const float* __restrict__ wp_base, const float* __restrict__ up_base,
    int ld, float bias, int b0, int n)
{
    float* sx = smem;           // [16][256]
    float* sh = smem + 4096;    // [16][512]
    {
        const float4* xg = (const float4*)x;        // x: read-only, normal (cached) loads
        float4* sx4 = (float4*)sx;
        for (int i = tid; i < 16 * 64; i += NTHR) {            // 2 iters
            const int r = i >> 6, c4 = i & 63;
            sx4[i] = xg[((b0 + r) * Tn + t) * 64 + c4];        // x[b][t][:]
        }
        // h: written by other wgs via agent stores -> agent 8B loads
        unsigned long long* sh8 = (unsigned long long*)sh;
        const unsigned long long* hg = (const unsigned long long*)hbuf;
        for (int i = tid; i < 16 * 256; i += NTHR) {           // 8 iters
            const int r = i >> 8, c2 = i & 255;
            sh8[i] = ld_agent_u64(&hg[((b0 + r) << 8) + c2]);  // h[b][:] (2 floats)
        }
    }
    __syncthreads();

    const int rg  = tid >> 6;                                  // 8 row-pairs
    const int ld2 = ld + ld, ld3 = ld2 + ld, ld4 = ld2 + ld2;
    float acc0 = bias, acc1 = bias;
    {   // x @ W, k = 0..255   (weights: normal loads, L2-resident across steps)
        const float* wp = wp_base;
        const float4* a0 = (const float4*)(sx + (rg << 1) * 256);
        const float4* a1 = a0 + 64;
        #pragma unroll 8
        for (int kk = 0; kk < 64; ++kk) {
            const float w0 = wp[0], w1 = wp[ld], w2 = wp[ld2], w3 = wp[ld3];
            wp += ld4;
            const float4 v0 = a0[kk], v1 = a1[kk];
            acc0 = fmaf(w0, v0.x, acc0); acc1 = fmaf(w0, v1.x, acc1);
            acc0 = fmaf(w1, v0.y, acc0); acc1 = fmaf(w1, v1.y, acc1);
            acc0 = fmaf(w2, v0.z, acc0); acc1 = fmaf(w2, v1.z, acc1);
            acc0 = fmaf(w3, v0.w, acc0); acc1 = fmaf(w3, v1.w, acc1);
        }
    }
    {   // h @ U, k = 0..511
        const float* up = up_base;
        const float4* a0 = (const float4*)(sh + (rg << 1) * 512);
        const float4* a1 = a0 + 128;
        #pragma unroll 8
        for (int kk = 0; kk < 128; ++kk) {
            const float w0 = up[0], w1 = up[ld], w2 = up[ld2], w3 = up[ld3];
            up += ld4;
            const float4 v0 = a0[kk], v1 = a1[kk];
            acc0 = fmaf(w0, v0.x, acc0); acc1 = fmaf(w0, v1.x, acc1);
            acc0 = fmaf(w1, v0.y, acc0); acc1 = fmaf(w1, v1.y, acc1);
            acc0 = fmaf(w2, v0.z, acc0); acc1 = fmaf(w2, v1.z, acc1);
            acc0 = fmaf(w3, v0.w, acc0); acc1 = fmaf(w3, v1.w, acc1);
        }
    }
    const int row = b0 + (rg << 1);
    st_agent_f32(&z[row * NCOL + n], acc0);        // cross-wg -> agent stores
    st_agent_f32(&z[(row + 1) * NCOL + n], acc1);
}

// Phase B for batch b: e = softmax(ze); c = f*(e . mem) + i*c~; h = o*tanh(c).
// chist[b][slot][u] circular: slot for c_s is s & 63 (wg-private: normal ld/st).
__device__ __forceinline__ void phaseB_body(
    int t, int b, int tid, float* esm,
    const float* __restrict__ z, float* __restrict__ chist,
    float* __restrict__ hbuf, float* __restrict__ out)
{
    if (tid < 64) {
        const float v = ld_agent_f32(&z[b * NCOL + 2048 + tid]);
        float m = v;
        #pragma unroll
        for (int off = 32; off; off >>= 1) m = fmaxf(m, __shfl_xor(m, off, 64));
        const float ex = __expf(v - m);
        float s = ex;
        #pragma unroll
        for (int off = 32; off; off >>= 1) s += __shfl_xor(s, off, 64);
        esm[tid] = ex / s;
    }
    __syncthreads();
    const int u = tid;
    const float* zb = z + b * NCOL;
    const float zi = ld_agent_f32(zb + u);
    const float zf = ld_agent_f32(zb + Un + u);
    const float zo = ld_agent_f32(zb + 2 * Un + u);
    const float zc = ld_agent_f32(zb + 3 * Un + u);
    float* ch = chist + ((b << 6) << 9) + u;
    float mc = 0.0f;
    #pragma unroll 8
    for (int j = 0; j < 64; ++j) {
        const int slot = (t + 63 - j) & 63;        // (t-1-j) mod 64
        mc = fmaf(esm[j], ch[slot << 9], mc);
    }
    const float ig  = sigmoidf_(zi);
    const float fg  = sigmoidf_(zf);
    const float og  = sigmoidf_(zo);
    const float ctl = tanhf(zc);
    const float cc  = fg * mc + ig * ctl;
    const float hh  = og * tanhf(cc);
    ch[(t & 63) << 9] = cc;                        // newest c -> slot t%64 (private)
    st_agent_f32(&hbuf[(b << 9) + u], hh);         // cross-wg -> agent store
    out[((b * Tn + t) << 9) + u] = hh;             // host-visible after kernel end
}

// ---------------- init kernel (stream-ordered before main) ----------------
__global__ __launch_bounds__(NTHR) void init_k(float* __restrict__ ws)
{
    unsigned* ctr = (unsigned*)ws;
    if (blockIdx.x == 0 && threadIdx.x == 0) *ctr = 0u;
    float* chist = ws + CTR_PAD + Z_FLOATS;
    for (int i = blockIdx.x * NTHR + threadIdx.x; i < CHIST_FLOATS + Bn * Un;
         i += gridDim.x * NTHR)
        chist[i] = 0.0f;                           // zero chist + hbuf
}

// ---------------- persistent main kernel (coop launch for residency;
//                  NO grid.sync — custom barrier) ----------------
__global__ __launch_bounds__(NTHR) void xlstm_coop(
    const float* __restrict__ x,
    const float* __restrict__ Wi, const float* __restrict__ Ui, const float* __restrict__ bi,
    const float* __restrict__ Wf, const float* __restrict__ Uf, const float* __restrict__ bf_,
    const float* __restrict__ Wo, const float* __restrict__ Uo, const float* __restrict__ bo,
    const float* __restrict__ Wc, const float* __restrict__ Uc, const float* __restrict__ bc,
    const float* __restrict__ We, const float* __restrict__ Ue, const float* __restrict__ be,
    float* __restrict__ out, float* __restrict__ ws)
{
    __shared__ float smem[12288];   // 48 KB
    unsigned* ctr = (unsigned*)ws;
    float* z     = ws + CTR_PAD;
    float* chist = z + Z_FLOATS;
    float* hbuf  = chist + CHIST_FLOATS;

    const int tid = threadIdx.x, wg = blockIdx.x;

    const float *wp, *up; int ld, b0, n; float bias;
    cfgA(wg, tid, Wi, Ui, bi, Wf, Uf, bf_, Wo, Uo, bo, Wc, Uc, bc, We, Ue, be,
         wp, up, ld, bias, b0, n);

    for (int t = 0; t < Tn; ++t) {
        phaseA_body(t, tid, smem, x, hbuf, z, wp, up, ld, bias, b0, n);
        gbar(ctr, (unsigned)(ABLK * (2 * t + 1)));
        if (wg < Bn) phaseB_body(t, wg, tid, smem, z, chist, hbuf, out);
        gbar(ctr, (unsigned)(ABLK * (2 * t + 2)));
    }
}

// ---------------- fallback multi-launch path (kernel-boundary fences
//                  provide the ordering; agent ops remain correct) ----------------
__global__ __launch_bounds__(NTHR) void stepA_k(
    int t, const float* __restrict__ x,
    const float* __restrict__ Wi, const float* __restrict__ Ui, const float* __restrict__ bi,
    const float* __restrict__ Wf, const float* __restrict__ Uf, const float* __restrict__ bf_,
    const float* __restrict__ Wo, const float* __restrict__ Uo, const float* __restrict__ bo,
    const float* __restrict__ Wc, const float* __restrict__ Uc, const float* __restrict__ bc,
    const float* __restrict__ We, const float* __restrict__ Ue, const float* __restrict__ be,
    float* __restrict__ ws)
{
    __shared__ float smem[12288];
    float* z     = ws + CTR_PAD;
    float* chist = z + Z_FLOATS;
    float* hbuf  = chist + CHIST_FLOATS;
    const float *wp, *up; int ld, b0, n; float bias;
    cfgA(blockIdx.x, threadIdx.x, Wi, Ui, bi, Wf, Uf, bf_, Wo, Uo, bo,
         Wc, Uc, bc, We, Ue, be, wp, up, ld, bias, b0, n);
    phaseA_body(t, threadIdx.x, smem, x, hbuf, z, wp, up, ld, bias, b0, n);
}

__global__ __launch_bounds__(NTHR) void stepB_k(
    int t, float* __restrict__ out, float* __restrict__ ws)
{
    __shared__ float esm[64];
    float* z     = ws + CTR_PAD;
    float* chist = z + Z_FLOATS;
    float* hbuf  = chist + CHIST_FLOATS;
    phaseB_body(t, blockIdx.x, threadIdx.x, esm, z, chist, hbuf, out);
}

extern "C" void kernel_launch(void* const* d_in, const int* in_sizes, int n_in,
                              void* d_out, int out_size, void* d_ws, size_t ws_size,
                              hipStream_t stream) {
    const float* x  = (const float*)d_in[0];
    const float* Wi = (const float*)d_in[1];
    const float* Ui = (const float*)d_in[2];
    const float* bi = (const float*)d_in[3];
    const float* Wf = (const float*)d_in[4];
    const float* Uf = (const float*)d_in[5];
    const float* bf = (const float*)d_in[6];
    const float* Wo = (const float*)d_in[7];
    const float* Uo = (const float*)d_in[8];
    const float* bo = (const float*)d_in[9];
    const float* Wc = (const float*)d_in[10];
    const float* Uc = (const float*)d_in[11];
    const float* bc = (const float*)d_in[12];
    const float* We = (const float*)d_in[13];
    const float* Ue = (const float*)d_in[14];
    const float* be = (const float*)d_in[15];
    float* out = (float*)d_out;
    float* ws  = (float*)d_ws;

    init_k<<<256, NTHR, 0, stream>>>(ws);

    void* args[] = { &x, &Wi, &Ui, &bi, &Wf, &Uf, &bf, &Wo, &Uo, &bo,
                     &Wc, &Uc, &bc, &We, &Ue, &be, &out, &ws };
    hipError_t e = hipLaunchCooperativeKernel((const void*)xlstm_coop,
                                              dim3(ABLK), dim3(NTHR), args, 0, stream);
    if (e != hipSuccess) {
        (void)hipGetLastError();   // clear sticky error; per-step fallback
        for (int t = 0; t < Tn; ++t) {
            stepA_k<<<ABLK, NTHR, 0, stream>>>(t, x, Wi, Ui, bi, Wf, Uf, bf,
                                               Wo, Uo, bo, Wc, Uc, bc, We, Ue, be, ws);
            stepB_k<<<Bn, NTHR, 0, stream>>>(t, out, ws);
        }
    }
}

// Round 4
// 11033.642 us; speedup vs baseline: 3.2680x; 2.6422x over previous
//
#include <hip/hip_runtime.h>

// Problem constants
#define Bn   64
#define Tn   512
#define Dn   256
#define Un   512
#define Mn   64
#define NCOL 2112                 // 4U + M
#define ABLK 68                   // 17 col-tiles (16 gate-tiles of 128 + 1 e-tile of 64) x 4 b-tiles(16)
#define NTHR 256                  // 4 waves
#define KB_N 24                   // K blocks of 32 (K = 768 = 256 x-rows + 512 h-rows)
#define NB_N 132                  // N blocks of 16 (2112 / 16)
#define LDA  776                  // LDS row stride in ushorts (768 + 8 pad -> 2-way-only bank conflicts)

#define CHIST_FLOATS (Bn * Mn * Un)        // 2097152
#define Z_FLOATS     (Bn * NCOL)           // 135168
#define HB_U32       (Bn * Un / 2)         // 16384 u32 (bf16 h)
#define BP_GROUPS    (KB_N * NB_N * 64)    // 202752 lane-groups of 8 bf16
#define CTR_PAD      64

// ws layout (floats): ctr[64] | z | chist | bcat[2112] | hbuf(bf16, 16384 f-worth) | Bp(bf16, 811008 f-worth)
// total ~12.3 MB.
//
// Coherence design (kept from R3): no cg::grid.sync (its buffer_inv was one problem);
// cross-wg data (z, hbuf, ctr) via agent-scope relaxed atomics; weights/x/chist/out
// normal cached ops. R4 change: weights bf16-packed (L2-resident: ~1.6 MB/XCD) and
// phase A on MFMA; h transported bf16; 17 wide col-tiles cut h duplication 4x.

typedef __attribute__((ext_vector_type(8))) short short8;
typedef __attribute__((ext_vector_type(4))) float f32x4;

__device__ __forceinline__ float sigmoidf_(float v) { return 1.0f / (1.0f + __expf(-v)); }

__device__ __forceinline__ unsigned short f2bf(float f) {   // RNE fp32 -> bf16
    unsigned u = __float_as_uint(f);
    return (unsigned short)((u + 0x7FFFu + ((u >> 16) & 1u)) >> 16);
}

__device__ __forceinline__ void st_agent_f32(float* p, float v) {
    __hip_atomic_store(p, v, __ATOMIC_RELAXED, __HIP_MEMORY_SCOPE_AGENT);
}
__device__ __forceinline__ float ld_agent_f32(const float* p) {
    return __hip_atomic_load(p, __ATOMIC_RELAXED, __HIP_MEMORY_SCOPE_AGENT);
}
__device__ __forceinline__ void st_agent_u32(unsigned* p, unsigned v) {
    __hip_atomic_store(p, v, __ATOMIC_RELAXED, __HIP_MEMORY_SCOPE_AGENT);
}
__device__ __forceinline__ unsigned ld_agent_u32(const unsigned* p) {
    return __hip_atomic_load(p, __ATOMIC_RELAXED, __HIP_MEMORY_SCOPE_AGENT);
}
__device__ __forceinline__ unsigned long long ld_agent_u64(const void* p) {
    return __hip_atomic_load((const unsigned long long*)p, __ATOMIC_RELAXED,
                             __HIP_MEMORY_SCOPE_AGENT);
}

// Grid barrier: monotonic counter, agent-scope relaxed; per-wave drain first.
__device__ __forceinline__ void gbar(unsigned* ctr, unsigned target) {
    __builtin_amdgcn_s_waitcnt(0);
    __syncthreads();
    if (threadIdx.x == 0) {
        __hip_atomic_fetch_add(ctr, 1u, __ATOMIC_RELAXED, __HIP_MEMORY_SCOPE_AGENT);
        while (__hip_atomic_load(ctr, __ATOMIC_RELAXED, __HIP_MEMORY_SCOPE_AGENT) < target)
            __builtin_amdgcn_s_sleep(1);
    }
    __syncthreads();
}

// ---------------- phase A: z[b-tile, n-tile] = [x_t | h] @ [W;U] + b via MFMA ----------------
// wg = ct*4 + bt.  ct 0..15: 128 cols (2 n-frags/wave); ct 16: e-block, 64 cols (1 n-frag/wave).
__device__ __forceinline__ void phaseA_body(
    int t, int wg, int tid, unsigned short* sA,
    const float* __restrict__ x, const unsigned* __restrict__ hbu,
    const unsigned short* __restrict__ Bp, const float* __restrict__ bcat,
    float* __restrict__ z)
{
    const int ct = wg >> 2, bt = wg & 3;
    const int b0 = bt << 4;

    // stage xh[16][768] as bf16 into LDS (row stride LDA=776)
    {
        const float4* xg = (const float4*)x;
        for (int i = tid; i < 16 * 64; i += NTHR) {               // x rows: 4 iters
            const int r = i >> 6, c4 = i & 63;
            const float4 v = xg[(((b0 + r) * Tn + t) << 6) + c4]; // x[b][t][4c4..+3]
            ushort4 o; o.x = f2bf(v.x); o.y = f2bf(v.y); o.z = f2bf(v.z); o.w = f2bf(v.w);
            *(ushort4*)(sA + r * LDA + (c4 << 2)) = o;
        }
        for (int i = tid; i < 16 * 256; i += NTHR) {              // h rows (bf16 pairs): 16 iters
            const int r = i >> 8, c2 = i & 255;
            const unsigned v = ld_agent_u32(&hbu[((b0 + r) << 8) + c2]);
            *(unsigned*)(sA + r * LDA + 256 + (c2 << 1)) = v;
        }
    }
    __syncthreads();

    const int wave = tid >> 6, lane = tid & 63;
    const int quad = lane >> 4, m16 = lane & 15;
    const unsigned short* aBase = sA + m16 * LDA + (quad << 3);
    const short8* Bp8 = (const short8*)Bp;

    if (ct < 16) {
        const int nb0 = (ct << 3) + (wave << 1);                  // 2 n-frags
        f32x4 acc0 = {0.f, 0.f, 0.f, 0.f}, acc1 = acc0;
        #pragma unroll 4
        for (int kb = 0; kb < KB_N; ++kb) {
            const short8 a  = *(const short8*)(aBase + (kb << 5));
            const short8 bv0 = Bp8[((kb * NB_N + nb0) << 6) + lane];
            const short8 bv1 = Bp8[((kb * NB_N + nb0 + 1) << 6) + lane];
            acc0 = __builtin_amdgcn_mfma_f32_16x16x32_bf16(a, bv0, acc0, 0, 0, 0);
            acc1 = __builtin_amdgcn_mfma_f32_16x16x32_bf16(a, bv1, acc1, 0, 0, 0);
        }
        const int n0 = (nb0 << 4) + m16;
        const float bias0 = bcat[n0], bias1 = bcat[n0 + 16];
        #pragma unroll
        for (int r = 0; r < 4; ++r) {
            const int row = b0 + (quad << 2) + r;
            st_agent_f32(&z[row * NCOL + n0],      acc0[r] + bias0);
            st_agent_f32(&z[row * NCOL + n0 + 16], acc1[r] + bias1);
        }
    } else {                                                      // e-block: nb = 128 + wave
        const int nb = 128 + wave;
        f32x4 acc = {0.f, 0.f, 0.f, 0.f};
        #pragma unroll 4
        for (int kb = 0; kb < KB_N; ++kb) {
            const short8 a  = *(const short8*)(aBase + (kb << 5));
            const short8 bv = Bp8[((kb * NB_N + nb) << 6) + lane];
            acc = __builtin_amdgcn_mfma_f32_16x16x32_bf16(a, bv, acc, 0, 0, 0);
        }
        const int n0 = (nb << 4) + m16;
        const float bias = bcat[n0];
        #pragma unroll
        for (int r = 0; r < 4; ++r) {
            const int row = b0 + (quad << 2) + r;
            st_agent_f32(&z[row * NCOL + n0], acc[r] + bias);
        }
    }
}

// ---------------- phase B: softmax memory read + gates (b = wg), 2 u per thread ----------------
__device__ __forceinline__ void phaseB_body(
    int t, int b, int tid, float* esm,
    const float* __restrict__ z, float* __restrict__ chist,
    unsigned* __restrict__ hbu, float* __restrict__ out)
{
    if (tid < 64) {
        const float v = ld_agent_f32(&z[b * NCOL + 2048 + tid]);
        float m = v;
        #pragma unroll
        for (int off = 32; off; off >>= 1) m = fmaxf(m, __shfl_xor(m, off, 64));
        const float ex = __expf(v - m);
        float s = ex;
        #pragma unroll
        for (int off = 32; off; off >>= 1) s += __shfl_xor(s, off, 64);
        esm[tid] = ex / s;
    }
    __syncthreads();

    const int u = tid << 1;                                       // u, u+1
    const float* zb = z + b * NCOL;
    unsigned long long w;
    w = ld_agent_u64(zb + u);            const float2 zi = *(float2*)&w;
    w = ld_agent_u64(zb + Un + u);       const float2 zf = *(float2*)&w;
    w = ld_agent_u64(zb + 2 * Un + u);   const float2 zo = *(float2*)&w;
    w = ld_agent_u64(zb + 3 * Un + u);   const float2 zc = *(float2*)&w;

    float* ch = chist + ((b << 6) << 9) + u;                      // chist[b][slot][u]
    float mcx = 0.f, mcy = 0.f;
    #pragma unroll 8
    for (int j = 0; j < 64; ++j) {
        const int slot = (t + 63 - j) & 63;                       // (t-1-j) mod 64
        const float2 cp = *(const float2*)(ch + (slot << 9));
        const float e = esm[j];
        mcx = fmaf(e, cp.x, mcx);
        mcy = fmaf(e, cp.y, mcy);
    }
    const float ccx = sigmoidf_(zf.x) * mcx + sigmoidf_(zi.x) * tanhf(zc.x);
    const float ccy = sigmoidf_(zf.y) * mcy + sigmoidf_(zi.y) * tanhf(zc.y);
    const float hhx = sigmoidf_(zo.x) * tanhf(ccx);
    const float hhy = sigmoidf_(zo.y) * tanhf(ccy);

    *(float2*)(ch + ((t & 63) << 9)) = make_float2(ccx, ccy);     // newest c (wg-private)
    st_agent_u32(&hbu[(b << 8) + tid], (unsigned)f2bf(hhx) | ((unsigned)f2bf(hhy) << 16));
    *(float2*)(out + ((b * Tn + t) << 9) + u) = make_float2(hhx, hhy);
}

// ---------------- init: zero state, pack bcat + bf16 MFMA-ordered weights ----------------
__global__ __launch_bounds__(NTHR) void init_k(
    const float* __restrict__ Wi, const float* __restrict__ Ui, const float* __restrict__ bi,
    const float* __restrict__ Wf, const float* __restrict__ Uf, const float* __restrict__ bf_,
    const float* __restrict__ Wo, const float* __restrict__ Uo, const float* __restrict__ bo,
    const float* __restrict__ Wc, const float* __restrict__ Uc, const float* __restrict__ bc,
    const float* __restrict__ We, const float* __restrict__ Ue, const float* __restrict__ be,
    float* __restrict__ ws)
{
    unsigned* ctr = (unsigned*)ws;
    float* z     = ws + CTR_PAD;
    float* chist = z + Z_FLOATS;
    float* bcat  = chist + CHIST_FLOATS;
    unsigned* hbu = (unsigned*)(bcat + NCOL);
    unsigned short* Bp = (unsigned short*)(hbu + HB_U32);

    const int idx = blockIdx.x * NTHR + threadIdx.x;
    const int stride = gridDim.x * NTHR;
    if (idx == 0) *ctr = 0u;

    for (int i = idx; i < CHIST_FLOATS + HB_U32; i += stride) {
        if (i < CHIST_FLOATS) chist[i] = 0.0f;
        else hbu[i - CHIST_FLOATS] = 0u;
    }
    const float* Wg[4] = {Wi, Wf, Wo, Wc};
    const float* Ug[4] = {Ui, Uf, Uo, Uc};
    const float* bg[4] = {bi, bf_, bo, bc};
    for (int n = idx; n < NCOL; n += stride) {
        const int seg = n >> 9;
        bcat[n] = (seg < 4) ? bg[seg][n & 511] : be[n - 2048];
    }
    // Bp[((kb*132+nb)*64+lane)*8 + j] = bf16( [W;U][k = kb*32 + (lane>>4)*8 + j][n = nb*16 + (lane&15)] )
    for (int g = idx; g < BP_GROUPS; g += stride) {
        const int lane = g & 63;
        const int t2 = g >> 6;
        const int nb = t2 % NB_N, kb = t2 / NB_N;
        const int n = (nb << 4) + (lane & 15);
        const int seg = n >> 9;
        const int cs = (seg < 4) ? (n & 511) : (n - 2048);
        const int kbase = (kb << 5) + ((lane >> 4) << 3);
        #pragma unroll
        for (int j = 0; j < 8; ++j) {
            const int k = kbase + j;
            float v;
            if (k < 256) v = (seg < 4) ? Wg[seg][(k << 9) + cs] : We[(k << 6) + cs];
            else { const int k2 = k - 256;
                   v = (seg < 4) ? Ug[seg][(k2 << 9) + cs] : Ue[(k2 << 6) + cs]; }
            Bp[(g << 3) + j] = f2bf(v);
        }
    }
}

// ---------------- persistent cooperative main ----------------
__global__ __launch_bounds__(NTHR) void xlstm_coop(
    const float* __restrict__ x, float* __restrict__ out, float* __restrict__ ws)
{
    __shared__ unsigned short sA[16 * LDA + 16];
    unsigned* ctr = (unsigned*)ws;
    float* z     = ws + CTR_PAD;
    float* chist = z + Z_FLOATS;
    float* bcat  = chist + CHIST_FLOATS;
    unsigned* hbu = (unsigned*)(bcat + NCOL);
    const unsigned short* Bp = (const unsigned short*)(hbu + HB_U32);

    const int tid = threadIdx.x, wg = blockIdx.x;

    for (int t = 0; t < Tn; ++t) {
        phaseA_body(t, wg, tid, sA, x, hbu, Bp, bcat, z);
        gbar(ctr, (unsigned)(ABLK * (2 * t + 1)));
        if (wg < Bn) phaseB_body(t, wg, tid, (float*)sA, z, chist, hbu, out);
        gbar(ctr, (unsigned)(ABLK * (2 * t + 2)));
    }
}

// ---------------- fallback multi-launch path ----------------
__global__ __launch_bounds__(NTHR) void stepA_k(
    int t, const float* __restrict__ x, float* __restrict__ ws)
{
    __shared__ unsigned short sA[16 * LDA + 16];
    float* z     = ws + CTR_PAD;
    float* chist = z + Z_FLOATS;
    float* bcat  = chist + CHIST_FLOATS;
    unsigned* hbu = (unsigned*)(bcat + NCOL);
    const unsigned short* Bp = (const unsigned short*)(hbu + HB_U32);
    phaseA_body(t, blockIdx.x, threadIdx.x, sA, x, hbu, Bp, bcat, z);
}

__global__ __launch_bounds__(NTHR) void stepB_k(
    int t, float* __restrict__ out, float* __restrict__ ws)
{
    __shared__ float esm[64];
    float* z     = ws + CTR_PAD;
    float* chist = z + Z_FLOATS;
    float* bcat  = chist + CHIST_FLOATS;
    unsigned* hbu = (unsigned*)(bcat + NCOL);
    phaseB_body(t, blockIdx.x, threadIdx.x, esm, z, chist, hbu, out);
}

extern "C" void kernel_launch(void* const* d_in, const int* in_sizes, int n_in,
                              void* d_out, int out_size, void* d_ws, size_t ws_size,
                              hipStream_t stream) {
    const float* x  = (const float*)d_in[0];
    const float* Wi = (const float*)d_in[1];
    const float* Ui = (const float*)d_in[2];
    const float* bi = (const float*)d_in[3];
    const float* Wf = (const float*)d_in[4];
    const float* Uf = (const float*)d_in[5];
    const float* bf = (const float*)d_in[6];
    const float* Wo = (const float*)d_in[7];
    const float* Uo = (const float*)d_in[8];
    const float* bo = (const float*)d_in[9];
    const float* Wc = (const float*)d_in[10];
    const float* Uc = (const float*)d_in[11];
    const float* bc = (const float*)d_in[12];
    const float* We = (const float*)d_in[13];
    const float* Ue = (const float*)d_in[14];
    const float* be = (const float*)d_in[15];
    float* out = (float*)d_out;
    float* ws  = (float*)d_ws;

    init_k<<<512, NTHR, 0, stream>>>(Wi, Ui, bi, Wf, Uf, bf, Wo, Uo, bo,
                                     Wc, Uc, bc, We, Ue, be, ws);

    void* args[] = { &x, &out, &ws };
    hipError_t e = hipLaunchCooperativeKernel((const void*)xlstm_coop,
                                              dim3(ABLK), dim3(NTHR), args, 0, stream);
    if (e != hipSuccess) {
        (void)hipGetLastError();   // clear sticky error; per-step fallback
        for (int t = 0; t < Tn; ++t) {
            stepA_k<<<ABLK, NTHR, 0, stream>>>(t, x, ws);
            stepB_k<<<Bn, NTHR, 0, stream>>>(t, out, ws);
        }
    }
}

// Round 6
// 4322.452 us; speedup vs baseline: 8.3420x; 2.5526x over previous
//
#include <hip/hip_runtime.h>

// Problem constants
#define Bn   64
#define Tn   512
#define Dn   256
#define Un   512
#define Mn   64
#define NTHR 256
#define GRID 132                  // 4 b-tiles x (32 u-tiles + 1 e-tile)

// ws layout (float index):
//   [0..1023]    counters (u32): hctr[bt] at bt*16, ectr[bt] at 256+bt*16
//   EG_OFF  (4096 f)     e_glob[bt][16][64] fp32
//   HB_OFF  (32768 f)    hbuf as u32 [2][64][256]  (bf16 h pairs, DOUBLE buffer
//                        -> needs 32768 u32; R5 reserved 16384 and buffer 1
//                        aliased chist uid-0 => NaN. FIXED.)
//   CHS_OFF (1048576 f)  chist bf16 [128 uid][256 tid][64 slot]  (wg-private)
//   BP_OFF  ushort area: BPU (1572864 sh) gate weights, BPE (49152 sh) e weights
// total 7.59 MB (< 9.06 MB proven available by R2).
#define EG_OFF    1024
#define HB_OFF    5120
#define CHS_OFF   37888
#define BP_OFF    1086464
#define BPU_SH    1572864
#define BPE_SH    49152

typedef __attribute__((ext_vector_type(8))) short short8;
typedef __attribute__((ext_vector_type(4))) float f32x4;
typedef unsigned long long ull;

__device__ __forceinline__ float sigmoidf_(float v) { return 1.0f / (1.0f + __expf(-v)); }

__device__ __forceinline__ unsigned short f2bf(float f) {   // RNE fp32 -> bf16
    unsigned u = __float_as_uint(f);
    return (unsigned short)((u + 0x7FFFu + ((u >> 16) & 1u)) >> 16);
}

__device__ __forceinline__ void st_agent_f32(float* p, float v) {
    __hip_atomic_store(p, v, __ATOMIC_RELAXED, __HIP_MEMORY_SCOPE_AGENT);
}
__device__ __forceinline__ float ld_agent_f32(const float* p) {
    return __hip_atomic_load(p, __ATOMIC_RELAXED, __HIP_MEMORY_SCOPE_AGENT);
}
__device__ __forceinline__ void st_agent_u32(unsigned* p, unsigned v) {
    __hip_atomic_store(p, v, __ATOMIC_RELAXED, __HIP_MEMORY_SCOPE_AGENT);
}
__device__ __forceinline__ unsigned ld_agent_u32(const unsigned* p) {
    return __hip_atomic_load(p, __ATOMIC_RELAXED, __HIP_MEMORY_SCOPE_AGENT);
}
__device__ __forceinline__ ull ld_agent_u64(const void* p) {
    return __hip_atomic_load((const ull*)p, __ATOMIC_RELAXED, __HIP_MEMORY_SCOPE_AGENT);
}

// point-to-point wait: one thread spins, wg waits at the barrier
__device__ __forceinline__ void wait_ge(unsigned* p, unsigned target) {
    __syncthreads();
    if (threadIdx.x == 0)
        while (ld_agent_u32(p) < target) __builtin_amdgcn_s_sleep(1);
    __syncthreads();
}
// publish: drain own stores per wave, align wg, one atomic add
__device__ __forceinline__ void publish(unsigned* p) {
    __builtin_amdgcn_s_waitcnt(0);
    __syncthreads();
    if (threadIdx.x == 0)
        __hip_atomic_fetch_add(p, 1u, __ATOMIC_RELAXED, __HIP_MEMORY_SCOPE_AGENT);
}

// shared staging: issue h (bf16, agent) into regs, stage x (cvt bf16) to sA rows 0..255,
// MFMA x-part while h flies, then h regs -> sA cols 256..767, MFMA h-part.
__device__ __forceinline__ f32x4 gemm_step(
    int t, int tid, int b0, unsigned short* sA,
    const float* __restrict__ x, const unsigned* __restrict__ hbu,
    const short8* __restrict__ Bw, const unsigned short* aBase)
{
    ull hreg[8];
    const ull* hg = (const ull*)(hbu + ((t & 1) << 14)) + (b0 << 7);
    #pragma unroll
    for (int j = 0; j < 8; ++j) hreg[j] = ld_agent_u64(hg + (j << 8) + tid);

    const float4* xg = (const float4*)x;
    #pragma unroll
    for (int i2 = 0; i2 < 4; ++i2) {
        const int i = (i2 << 8) + tid;
        const int rr = i >> 6, c4 = i & 63;
        const float4 v = xg[(((b0 + rr) * Tn + t) << 6) + c4];
        ushort4 o; o.x = f2bf(v.x); o.y = f2bf(v.y); o.z = f2bf(v.z); o.w = f2bf(v.w);
        *(ushort4*)(sA + rr * 776 + (c4 << 2)) = o;
    }
    __syncthreads();

    f32x4 acc = {0.f, 0.f, 0.f, 0.f};
    #pragma unroll
    for (int kb = 0; kb < 8; ++kb) {        // x-part (k 0..255), h still in flight
        const short8 a = *(const short8*)(aBase + (kb << 5));
        acc = __builtin_amdgcn_mfma_f32_16x16x32_bf16(a, Bw[kb << 6], acc, 0, 0, 0);
    }
    #pragma unroll
    for (int j = 0; j < 8; ++j) {           // h regs -> LDS (compiler waits vmcnt)
        const int f = (j << 8) + tid;
        *(ull*)(sA + (f >> 7) * 776 + 256 + ((f & 127) << 2)) = hreg[j];
    }
    __syncthreads();
    #pragma unroll
    for (int kb = 8; kb < 24; ++kb) {       // h-part (k 256..767)
        const short8 a = *(const short8*)(aBase + (kb << 5));
        acc = __builtin_amdgcn_mfma_f32_16x16x32_bf16(a, Bw[kb << 6], acc, 0, 0, 0);
    }
    return acc;
}

__global__ __launch_bounds__(NTHR) void xlstm_k(
    const float* __restrict__ x,
    const float* __restrict__ bi, const float* __restrict__ bf_,
    const float* __restrict__ bo, const float* __restrict__ bc,
    const float* __restrict__ be,
    float* __restrict__ out, float* __restrict__ ws)
{
    __shared__ unsigned short sA[16 * 776];  // 48.5 KB: xh tile bf16 (row pad 8)
    __shared__ float zs[1152];               // u-wg: zs[4][16][16]; e-wg: zel 16x68
    __shared__ float esm[16 * 68];           // u-wg: e staged; e-wg: sbe in [0..63]

    unsigned* ctr = (unsigned*)ws;
    float* EG = ws + EG_OFF;
    unsigned* hbu = (unsigned*)(ws + HB_OFF);
    unsigned short* CHSu = (unsigned short*)(ws + CHS_OFF);
    const unsigned short* BPU = (const unsigned short*)(ws + BP_OFF);
    const unsigned short* BPE = BPU + BPU_SH;

    const int tid = threadIdx.x, wg = blockIdx.x;
    const int bt = wg / 33, r = wg % 33;
    const int b0 = bt << 4;
    const int lane = tid & 63, w = tid >> 6;       // wave = gate (u-wg) / m-frag (e-wg)
    const int quad = lane >> 4, m16 = lane & 15;
    unsigned* hc = ctr + bt * 16;
    unsigned* ec = ctr + 256 + bt * 16;
    const unsigned short* aBase = sA + m16 * 776 + (quad << 3);

    if (r < 32) {
        // ================= u-wg: 16b x 16u x 4 gates =================
        const int u0 = r << 4;
        const int uid = (bt << 5) + r;
        const int bb = tid >> 4, uu = tid & 15;
        unsigned short* ch = CHSu + uid * 16384 + tid * 64;  // 64 bf16 slots (private)
        const float bia_i = bi[u0 + uu], bia_f = bf_[u0 + uu];
        const float bia_o = bo[u0 + uu], bia_c = bc[u0 + uu];
        const short8* Bw = (const short8*)BPU + (r * 4 + w) * 24 * 64 + lane;
        float* outp = out + (ull)((b0 + bb) * Tn) * 512 + u0 + uu;

        for (int t = 0; t < Tn; ++t) {
            if (t) wait_ge(hc, (unsigned)(t << 5));          // all 32 u-wgs wrote h_t
            f32x4 acc = gemm_step(t, tid, b0, sA, x, hbu, Bw, aBase);

            #pragma unroll
            for (int i = 0; i < 4; ++i)                      // gate exchange via LDS
                zs[(w << 8) + ((quad << 2) + i) * 16 + m16] = acc[i];

            wait_ge(ec, (unsigned)(t + 1));                  // e ready (also fences zs)
            #pragma unroll
            for (int j = 0; j < 4; ++j) {                    // stage e[16][64] fp32
                const int idx = (j << 8) + tid;
                esm[(idx >> 6) * 68 + (idx & 63)] = ld_agent_f32(EG + (bt << 10) + idx);
            }
            __syncthreads();

            const float zi = zs[tid] + bia_i;
            const float zf = zs[256 + tid] + bia_f;
            const float zo = zs[512 + tid] + bia_o;
            const float zc = zs[768 + tid] + bia_c;
            float mc = 0.f;
            const uint4* chv = (const uint4*)ch;
            const float* eb = esm + bb * 68;
            const int jb = t + 63;                           // e index j = (t-1-slot) mod 64
            #pragma unroll
            for (int q = 0; q < 8; ++q) {                    // 8 slots per uint4 (bf16)
                const uint4 v = chv[q];
                const int s = q << 3;
                mc = fmaf(__uint_as_float(v.x << 16),         eb[(jb - s) & 63], mc);
                mc = fmaf(__uint_as_float(v.x & 0xFFFF0000u), eb[(jb - s - 1) & 63], mc);
                mc = fmaf(__uint_as_float(v.y << 16),         eb[(jb - s - 2) & 63], mc);
                mc = fmaf(__uint_as_float(v.y & 0xFFFF0000u), eb[(jb - s - 3) & 63], mc);
                mc = fmaf(__uint_as_float(v.z << 16),         eb[(jb - s - 4) & 63], mc);
                mc = fmaf(__uint_as_float(v.z & 0xFFFF0000u), eb[(jb - s - 5) & 63], mc);
                mc = fmaf(__uint_as_float(v.w << 16),         eb[(jb - s - 6) & 63], mc);
                mc = fmaf(__uint_as_float(v.w & 0xFFFF0000u), eb[(jb - s - 7) & 63], mc);
            }
            const float cc = sigmoidf_(zf) * mc + sigmoidf_(zi) * tanhf(zc);
            const float hh = sigmoidf_(zo) * tanhf(cc);
            ch[t & 63] = f2bf(cc);                           // newest c (bf16, private)
            outp[t << 9] = hh;                               // h from unrounded cc
            const float nh = __shfl_xor(hh, 1);
            if (!(tid & 1)) {                                // pack 2 u's -> u32 bf16
                const unsigned v = (unsigned)f2bf(hh) | ((unsigned)f2bf(nh) << 16);
                st_agent_u32(hbu + (((t + 1) & 1) << 14) + ((b0 + bb) << 8)
                             + ((u0 + uu) >> 1), v);
            }
            publish(hc);
        }
    } else {
        // ================= e-wg: 16b x 64 e-cols + softmax =================
        if (tid < 64) esm[tid] = be[tid];                    // sbe
        const short8* Bw = (const short8*)BPE + w * 24 * 64 + lane;
        const int bb = tid >> 4, l = tid & 15;

        for (int t = 0; t < Tn; ++t) {
            if (t) wait_ge(hc, (unsigned)(t << 5));
            f32x4 acc = gemm_step(t, tid, b0, sA, x, hbu, Bw, aBase);

            #pragma unroll
            for (int i = 0; i < 4; ++i)                      // zel[16][68]
                zs[((quad << 2) + i) * 68 + (w << 4) + m16] = acc[i];
            __syncthreads();

            const float* zb = zs + bb * 68;                  // softmax over 64 (16-lane grp)
            float v0 = zb[l]      + esm[l];
            float v1 = zb[l + 16] + esm[l + 16];
            float v2 = zb[l + 32] + esm[l + 32];
            float v3 = zb[l + 48] + esm[l + 48];
            float mx = fmaxf(fmaxf(v0, v1), fmaxf(v2, v3));
            #pragma unroll
            for (int off = 8; off; off >>= 1) mx = fmaxf(mx, __shfl_xor(mx, off, 16));
            const float e0 = __expf(v0 - mx), e1 = __expf(v1 - mx);
            const float e2 = __expf(v2 - mx), e3 = __expf(v3 - mx);
            float ssum = e0 + e1 + e2 + e3;
            #pragma unroll
            for (int off = 8; off; off >>= 1) ssum += __shfl_xor(ssum, off, 16);
            const float inv = 1.0f / ssum;
            float* eg = EG + (bt << 10) + (bb << 6);
            st_agent_f32(eg + l,      e0 * inv);
            st_agent_f32(eg + l + 16, e1 * inv);
            st_agent_f32(eg + l + 32, e2 * inv);
            st_agent_f32(eg + l + 48, e3 * inv);
            publish(ec);
            __syncthreads();                                 // protect zs/esm reuse
        }
    }
}

// ---------------- init: zero state/counters, pack bf16 MFMA-ordered weights ----------------
__global__ __launch_bounds__(NTHR) void init_k(
    const float* __restrict__ Wi, const float* __restrict__ Ui,
    const float* __restrict__ Wf, const float* __restrict__ Uf,
    const float* __restrict__ Wo, const float* __restrict__ Uo,
    const float* __restrict__ Wc, const float* __restrict__ Uc,
    const float* __restrict__ We, const float* __restrict__ Ue,
    float* __restrict__ ws)
{
    const int idx = blockIdx.x * NTHR + threadIdx.x;
    const int stride = gridDim.x * NTHR;
    unsigned* ctr = (unsigned*)ws;
    for (int i = idx; i < 512; i += stride) ctr[i] = 0u;
    unsigned* hbu = (unsigned*)(ws + HB_OFF);
    for (int i = idx; i < 32768; i += stride) hbu[i] = 0u;   // both h buffers = 0
    float* CHS = ws + CHS_OFF;
    for (int i = idx; i < 1048576; i += stride) CHS[i] = 0.0f;  // bf16 chist = 0

    unsigned short* BPU = (unsigned short*)(ws + BP_OFF);
    unsigned short* BPE = BPU + BPU_SH;
    const float* Wg[4] = {Wi, Wf, Wo, Wc};
    const float* Ug[4] = {Ui, Uf, Uo, Uc};
    // BPU[((rr*4+w2)*24+kb)*64+lane][j] = bf16([W;U]_gate_w2[k=kb*32+(lane>>4)*8+j][rr*16+(lane&15)])
    for (int g = idx; g < 196608; g += stride) {
        const int lane = g & 63, rest = g >> 6;
        const int kb = rest % 24, rest2 = rest / 24;
        const int w2 = rest2 & 3, rr = rest2 >> 2;
        const int cs = (rr << 4) + (lane & 15);
        const int kbase = (kb << 5) + ((lane >> 4) << 3);
        #pragma unroll
        for (int j = 0; j < 8; ++j) {
            const int k = kbase + j;
            const float v = (k < 256) ? Wg[w2][(k << 9) + cs]
                                      : Ug[w2][((k - 256) << 9) + cs];
            BPU[(g << 3) + j] = f2bf(v);
        }
    }
    for (int g = idx; g < 6144; g += stride) {
        const int lane = g & 63, rest = g >> 6;
        const int kb = rest % 24, w2 = rest / 24;
        const int cs = (w2 << 4) + (lane & 15);
        const int kbase = (kb << 5) + ((lane >> 4) << 3);
        #pragma unroll
        for (int j = 0; j < 8; ++j) {
            const int k = kbase + j;
            const float v = (k < 256) ? We[(k << 6) + cs] : Ue[((k - 256) << 6) + cs];
            BPE[(g << 3) + j] = f2bf(v);
        }
    }
}

extern "C" void kernel_launch(void* const* d_in, const int* in_sizes, int n_in,
                              void* d_out, int out_size, void* d_ws, size_t ws_size,
                              hipStream_t stream) {
    const float* x  = (const float*)d_in[0];
    const float* Wi = (const float*)d_in[1];
    const float* Ui = (const float*)d_in[2];
    const float* bi = (const float*)d_in[3];
    const float* Wf = (const float*)d_in[4];
    const float* Uf = (const float*)d_in[5];
    const float* bf = (const float*)d_in[6];
    const float* Wo = (const float*)d_in[7];
    const float* Uo = (const float*)d_in[8];
    const float* bo = (const float*)d_in[9];
    const float* Wc = (const float*)d_in[10];
    const float* Uc = (const float*)d_in[11];
    const float* bc = (const float*)d_in[12];
    const float* We = (const float*)d_in[13];
    const float* Ue = (const float*)d_in[14];
    const float* be = (const float*)d_in[15];
    float* out = (float*)d_out;
    float* ws  = (float*)d_ws;

    init_k<<<512, NTHR, 0, stream>>>(Wi, Ui, Wf, Uf, Wo, Uo, Wc, Uc, We, Ue, ws);

    void* args[] = { &x, &bi, &bf, &bo, &bc, &be, &out, &ws };
    hipError_t e = hipLaunchCooperativeKernel((const void*)xlstm_k,
                                              dim3(GRID), dim3(NTHR), args, 0, stream);
    if (e != hipSuccess) {
        (void)hipGetLastError();   // 132 wgs co-reside trivially; plain launch fallback
        xlstm_k<<<GRID, NTHR, 0, stream>>>(x, bi, bf, bo, bc, be, out, ws);
    }
}

// Round 7
// 3060.760 us; speedup vs baseline: 11.7807x; 1.4122x over previous
//
#include <hip/hip_runtime.h>

// Problem constants
#define Bn   64
#define Tn   512
#define Dn   256
#define Un   512
#define Mn   64
#define NTHR 256
#define GRID 128                  // 4 b-tiles x 32 u-tiles (e fused into every wg)

// ws layout (float index) — identical to R6 (EG area now unused):
//   [0..1023]    flags (u32): flags[bt*32 + r] at ws[0..127]
//   EG_OFF  (4096 f)     (unused in R7)
//   HB_OFF  (32768 f)    hbuf as u32 [2][64][256]  (bf16 h pairs, double buffer)
//   CHS_OFF (1048576 f)  chist bf16 [128 wg][256 tid][64 slot]  (wg-private)
//   BP_OFF  ushort area: BPU (1572864 sh) gate weights, BPE (49152 sh) e weights
// total 7.59 MB (< 9.06 MB proven available by R2).
#define EG_OFF    1024
#define HB_OFF    5120
#define CHS_OFF   37888
#define BP_OFF    1086464
#define BPU_SH    1572864
#define BPE_SH    49152

typedef __attribute__((ext_vector_type(8))) short short8;
typedef __attribute__((ext_vector_type(4))) float f32x4;
typedef unsigned long long ull;

__device__ __forceinline__ float sigmoidf_(float v) { return 1.0f / (1.0f + __expf(-v)); }
__device__ __forceinline__ float tanhf_(float v) {   // hw-exp tanh; |v| small here
    const float e = __expf(2.0f * v);
    return (e - 1.0f) / (e + 1.0f);
}

__device__ __forceinline__ unsigned short f2bf(float f) {   // RNE fp32 -> bf16
    unsigned u = __float_as_uint(f);
    return (unsigned short)((u + 0x7FFFu + ((u >> 16) & 1u)) >> 16);
}

__device__ __forceinline__ void st_agent_u32(unsigned* p, unsigned v) {
    __hip_atomic_store(p, v, __ATOMIC_RELAXED, __HIP_MEMORY_SCOPE_AGENT);
}
__device__ __forceinline__ unsigned ld_agent_u32(const unsigned* p) {
    return __hip_atomic_load(p, __ATOMIC_RELAXED, __HIP_MEMORY_SCOPE_AGENT);
}
__device__ __forceinline__ ull ld_agent_u64(const void* p) {
    return __hip_atomic_load((const ull*)p, __ATOMIC_RELAXED, __HIP_MEMORY_SCOPE_AGENT);
}

__global__ __launch_bounds__(NTHR) void xlstm_k(
    const float* __restrict__ x,
    const float* __restrict__ bi, const float* __restrict__ bf_,
    const float* __restrict__ bo, const float* __restrict__ bc,
    const float* __restrict__ be,
    float* __restrict__ out, float* __restrict__ ws)
{
    __shared__ unsigned short sA[16 * 776];  // 24.8 KB xh tile bf16 (row pad 8)
    __shared__ float zs[1024];               // gate z [4 gate][16 b][16 u]
    __shared__ float zel[16 * 68];           // ze [16 b][64 e] (pad 68)
    __shared__ float esm[16 * 68];           // e   [16 b][64]  (pad 68)
    __shared__ float sbe[64];                // be staged

    unsigned* flags = (unsigned*)ws;
    unsigned* hbu = (unsigned*)(ws + HB_OFF);
    unsigned short* CHSu = (unsigned short*)(ws + CHS_OFF);
    const unsigned short* BPU = (const unsigned short*)(ws + BP_OFF);
    const unsigned short* BPE = BPU + BPU_SH;

    const int tid = threadIdx.x, wg = blockIdx.x;
    const int bt = wg >> 5, r = wg & 31;
    const int b0 = bt << 4, u0 = r << 4;
    const int lane = tid & 63, w = tid >> 6;       // wave = gate index
    const int quad = lane >> 4, m16 = lane & 15;
    const unsigned short* aBase = sA + m16 * 776 + (quad << 3);
    unsigned* myflag = flags + (bt << 5) + r;
    unsigned* bflags = flags + (bt << 5);

    const int bb = tid >> 4, uu = tid & 15;
    unsigned short* ch = CHSu + wg * 16384 + tid * 64;   // 64 bf16 c-slots (private)
    const float bia_i = bi[u0 + uu], bia_f = bf_[u0 + uu];
    const float bia_o = bo[u0 + uu], bia_c = bc[u0 + uu];
    const short8* Bg = (const short8*)BPU + (r * 4 + w) * 24 * 64 + lane;
    const short8* Be = (const short8*)BPE + w * 24 * 64 + lane;
    float* outp = out + (ull)((b0 + bb) * Tn) * 512 + u0 + uu;
    const float4* xg = (const float4*)x;

    if (tid < 64) sbe[tid] = be[tid];

    for (int t = 0; t < Tn; ++t) {
        // -------- x prefetch (no h dependency; flies during the wait) --------
        float4 xv[4];
        #pragma unroll
        for (int i2 = 0; i2 < 4; ++i2) {
            const int i = (i2 << 8) + tid;
            xv[i2] = xg[(((b0 + (i >> 6)) * Tn + t) << 6) + (i & 63)];
        }
        // -------- single cross-wg wait: all 32 u-wgs of bt published h_{t-1} --------
        if (t) {
            if (tid < 32)
                while (ld_agent_u32(bflags + tid) < (unsigned)t)
                    __builtin_amdgcn_s_sleep(1);
            __syncthreads();
        }
        // -------- h agent loads (issue early, consumed after x-part MFMAs) --------
        ull hreg[8];
        const ull* hg = (const ull*)(hbu + ((t & 1) << 14)) + (b0 << 7);
        #pragma unroll
        for (int j = 0; j < 8; ++j) hreg[j] = ld_agent_u64(hg + (j << 8) + tid);

        // -------- stage x regs -> sA (bf16) --------
        #pragma unroll
        for (int i2 = 0; i2 < 4; ++i2) {
            const int i = (i2 << 8) + tid;
            ushort4 o; o.x = f2bf(xv[i2].x); o.y = f2bf(xv[i2].y);
            o.z = f2bf(xv[i2].z); o.w = f2bf(xv[i2].w);
            *(ushort4*)(sA + (i >> 6) * 776 + ((i & 63) << 2)) = o;
        }
        __syncthreads();

        // -------- GEMM: gate (this wave's gate) + e, fused --------
        f32x4 ag = {0.f, 0.f, 0.f, 0.f}, ae = ag;
        #pragma unroll
        for (int kb = 0; kb < 8; ++kb) {        // x-part; h still in flight
            const short8 a = *(const short8*)(aBase + (kb << 5));
            ag = __builtin_amdgcn_mfma_f32_16x16x32_bf16(a, Bg[kb << 6], ag, 0, 0, 0);
            ae = __builtin_amdgcn_mfma_f32_16x16x32_bf16(a, Be[kb << 6], ae, 0, 0, 0);
        }
        #pragma unroll
        for (int j = 0; j < 8; ++j) {           // h regs -> LDS
            const int f = (j << 8) + tid;
            *(ull*)(sA + (f >> 7) * 776 + 256 + ((f & 127) << 2)) = hreg[j];
        }
        __syncthreads();
        #pragma unroll
        for (int kb = 8; kb < 24; ++kb) {       // h-part
            const short8 a = *(const short8*)(aBase + (kb << 5));
            ag = __builtin_amdgcn_mfma_f32_16x16x32_bf16(a, Bg[kb << 6], ag, 0, 0, 0);
            ae = __builtin_amdgcn_mfma_f32_16x16x32_bf16(a, Be[kb << 6], ae, 0, 0, 0);
        }

        // -------- exchange: gate z + ze into LDS --------
        #pragma unroll
        for (int i = 0; i < 4; ++i) {
            zs[(w << 8) + ((quad << 2) + i) * 16 + m16] = ag[i];
            zel[((quad << 2) + i) * 68 + (w << 4) + m16] = ae[i];
        }
        __syncthreads();

        // -------- local softmax over ze (16-lane groups per b) --------
        {
            const float* zb = zel + bb * 68;
            const int l = uu;
            float v0 = zb[l]      + sbe[l];
            float v1 = zb[l + 16] + sbe[l + 16];
            float v2 = zb[l + 32] + sbe[l + 32];
            float v3 = zb[l + 48] + sbe[l + 48];
            float mx = fmaxf(fmaxf(v0, v1), fmaxf(v2, v3));
            #pragma unroll
            for (int off = 8; off; off >>= 1) mx = fmaxf(mx, __shfl_xor(mx, off, 16));
            const float e0 = __expf(v0 - mx), e1 = __expf(v1 - mx);
            const float e2 = __expf(v2 - mx), e3 = __expf(v3 - mx);
            float ssum = e0 + e1 + e2 + e3;
            #pragma unroll
            for (int off = 8; off; off >>= 1) ssum += __shfl_xor(ssum, off, 16);
            const float inv = 1.0f / ssum;
            esm[bb * 68 + l]      = e0 * inv;
            esm[bb * 68 + l + 16] = e1 * inv;
            esm[bb * 68 + l + 32] = e2 * inv;
            esm[bb * 68 + l + 48] = e3 * inv;
        }
        __syncthreads();

        // -------- gates + 64-tap memory read + state update --------
        const float zi = zs[tid] + bia_i;
        const float zf = zs[256 + tid] + bia_f;
        const float zo = zs[512 + tid] + bia_o;
        const float zc = zs[768 + tid] + bia_c;
        float mc = 0.f;
        const uint4* chv = (const uint4*)ch;
        const float* eb = esm + bb * 68;
        const int jb = t + 63;                  // e index j = (t-1-slot) mod 64
        #pragma unroll
        for (int q = 0; q < 8; ++q) {           // 8 bf16 slots per uint4
            const uint4 v = chv[q];
            const int s = q << 3;
            mc = fmaf(__uint_as_float(v.x << 16),         eb[(jb - s) & 63], mc);
            mc = fmaf(__uint_as_float(v.x & 0xFFFF0000u), eb[(jb - s - 1) & 63], mc);
            mc = fmaf(__uint_as_float(v.y << 16),         eb[(jb - s - 2) & 63], mc);
            mc = fmaf(__uint_as_float(v.y & 0xFFFF0000u), eb[(jb - s - 3) & 63], mc);
            mc = fmaf(__uint_as_float(v.z << 16),         eb[(jb - s - 4) & 63], mc);
            mc = fmaf(__uint_as_float(v.z & 0xFFFF0000u), eb[(jb - s - 5) & 63], mc);
            mc = fmaf(__uint_as_float(v.w << 16),         eb[(jb - s - 6) & 63], mc);
            mc = fmaf(__uint_as_float(v.w & 0xFFFF0000u), eb[(jb - s - 7) & 63], mc);
        }
        const float cc = sigmoidf_(zf) * mc + sigmoidf_(zi) * tanhf_(zc);
        const float hh = sigmoidf_(zo) * tanhf_(cc);
        ch[t & 63] = f2bf(cc);                  // newest c (bf16, wg-private)
        outp[t << 9] = hh;                      // h from unrounded cc
        const float nh = __shfl_xor(hh, 1);
        if (!(tid & 1)) {                       // pack 2 u's -> u32 bf16 (agent)
            const unsigned v = (unsigned)f2bf(hh) | ((unsigned)f2bf(nh) << 16);
            st_agent_u32(hbu + (((t + 1) & 1) << 14) + ((b0 + bb) << 8)
                         + ((u0 + uu) >> 1), v);
        }
        // -------- publish: drain stores, align wg, set own flag (no RMW) --------
        __builtin_amdgcn_s_waitcnt(0);
        __syncthreads();
        if (tid == 0) st_agent_u32(myflag, (unsigned)(t + 1));
    }
}

// ---------------- init: zero state/flags, pack bf16 MFMA-ordered weights ----------------
__global__ __launch_bounds__(NTHR) void init_k(
    const float* __restrict__ Wi, const float* __restrict__ Ui,
    const float* __restrict__ Wf, const float* __restrict__ Uf,
    const float* __restrict__ Wo, const float* __restrict__ Uo,
    const float* __restrict__ Wc, const float* __restrict__ Uc,
    const float* __restrict__ We, const float* __restrict__ Ue,
    float* __restrict__ ws)
{
    const int idx = blockIdx.x * NTHR + threadIdx.x;
    const int stride = gridDim.x * NTHR;
    unsigned* ctr = (unsigned*)ws;
    for (int i = idx; i < 512; i += stride) ctr[i] = 0u;
    unsigned* hbu = (unsigned*)(ws + HB_OFF);
    for (int i = idx; i < 32768; i += stride) hbu[i] = 0u;   // both h buffers = 0
    float* CHS = ws + CHS_OFF;
    for (int i = idx; i < 1048576; i += stride) CHS[i] = 0.0f;  // bf16 chist = 0

    unsigned short* BPU = (unsigned short*)(ws + BP_OFF);
    unsigned short* BPE = BPU + BPU_SH;
    const float* Wg[4] = {Wi, Wf, Wo, Wc};
    const float* Ug[4] = {Ui, Uf, Uo, Uc};
    // BPU[((rr*4+w2)*24+kb)*64+lane][j] = bf16([W;U]_gate_w2[k=kb*32+(lane>>4)*8+j][rr*16+(lane&15)])
    for (int g = idx; g < 196608; g += stride) {
        const int lane = g & 63, rest = g >> 6;
        const int kb = rest % 24, rest2 = rest / 24;
        const int w2 = rest2 & 3, rr = rest2 >> 2;
        const int cs = (rr << 4) + (lane & 15);
        const int kbase = (kb << 5) + ((lane >> 4) << 3);
        #pragma unroll
        for (int j = 0; j < 8; ++j) {
            const int k = kbase + j;
            const float v = (k < 256) ? Wg[w2][(k << 9) + cs]
                                      : Ug[w2][((k - 256) << 9) + cs];
            BPU[(g << 3) + j] = f2bf(v);
        }
    }
    for (int g = idx; g < 6144; g += stride) {
        const int lane = g & 63, rest = g >> 6;
        const int kb = rest % 24, w2 = rest / 24;
        const int cs = (w2 << 4) + (lane & 15);
        const int kbase = (kb << 5) + ((lane >> 4) << 3);
        #pragma unroll
        for (int j = 0; j < 8; ++j) {
            const int k = kbase + j;
            const float v = (k < 256) ? We[(k << 6) + cs] : Ue[((k - 256) << 6) + cs];
            BPE[(g << 3) + j] = f2bf(v);
        }
    }
}

extern "C" void kernel_launch(void* const* d_in, const int* in_sizes, int n_in,
                              void* d_out, int out_size, void* d_ws, size_t ws_size,
                              hipStream_t stream) {
    const float* x  = (const float*)d_in[0];
    const float* Wi = (const float*)d_in[1];
    const float* Ui = (const float*)d_in[2];
    const float* bi = (const float*)d_in[3];
    const float* Wf = (const float*)d_in[4];
    const float* Uf = (const float*)d_in[5];
    const float* bf = (const float*)d_in[6];
    const float* Wo = (const float*)d_in[7];
    const float* Uo = (const float*)d_in[8];
    const float* bo = (const float*)d_in[9];
    const float* Wc = (const float*)d_in[10];
    const float* Uc = (const float*)d_in[11];
    const float* bc = (const float*)d_in[12];
    const float* We = (const float*)d_in[13];
    const float* Ue = (const float*)d_in[14];
    const float* be = (const float*)d_in[15];
    float* out = (float*)d_out;
    float* ws  = (float*)d_ws;

    init_k<<<512, NTHR, 0, stream>>>(Wi, Ui, Wf, Uf, Wo, Uo, Wc, Uc, We, Ue, ws);

    void* args[] = { &x, &bi, &bf, &bo, &bc, &be, &out, &ws };
    hipError_t e = hipLaunchCooperativeKernel((const void*)xlstm_k,
                                              dim3(GRID), dim3(NTHR), args, 0, stream);
    if (e != hipSuccess) {
        (void)hipGetLastError();   // 128 wgs co-reside trivially; plain launch fallback
        xlstm_k<<<GRID, NTHR, 0, stream>>>(x, bi, bf, bo, bc, be, out, ws);
    }
}

// Round 8
// 2814.749 us; speedup vs baseline: 12.8103x; 1.0874x over previous
//
#include <hip/hip_runtime.h>

// Problem constants
#define Bn   64
#define Tn   512
#define Dn   256
#define Un   512
#define Mn   64
#define NTHR 256
#define GRID 128                  // 4 b-tiles x 32 u-tiles (e fused into every wg)

// ws layout (float index):
//   [0..127]     flags (u32): flags[bt*32 + r]
//   HB_OFF  (32768 f)  hbuf as u32 [2][64][256]  (bf16 h pairs, double buffer)
//   BP_OFF  ushort area: BPU (1572864 sh) gate weights, BPE (49152 sh) e weights
// total ~3.4 MB.  chist now lives in LDS (32 KB/wg, zero-initialized in-kernel).
#define HB_OFF    5120
#define BP_OFF    37888
#define BPU_SH    1572864
#define BPE_SH    49152

typedef __attribute__((ext_vector_type(8))) short short8;
typedef __attribute__((ext_vector_type(4))) float f32x4;
typedef unsigned long long ull;

__device__ __forceinline__ float sigmoidf_(float v) { return 1.0f / (1.0f + __expf(-v)); }
__device__ __forceinline__ float tanhf_(float v) {   // hw-exp tanh; |v| small here
    const float e = __expf(2.0f * v);
    return (e - 1.0f) / (e + 1.0f);
}

__device__ __forceinline__ unsigned short f2bf(float f) {   // RNE fp32 -> bf16
    unsigned u = __float_as_uint(f);
    return (unsigned short)((u + 0x7FFFu + ((u >> 16) & 1u)) >> 16);
}

__device__ __forceinline__ void st_agent_u32(unsigned* p, unsigned v) {
    __hip_atomic_store(p, v, __ATOMIC_RELAXED, __HIP_MEMORY_SCOPE_AGENT);
}
__device__ __forceinline__ unsigned ld_agent_u32(const unsigned* p) {
    return __hip_atomic_load(p, __ATOMIC_RELAXED, __HIP_MEMORY_SCOPE_AGENT);
}
__device__ __forceinline__ ull ld_agent_u64(const void* p) {
    return __hip_atomic_load((const ull*)p, __ATOMIC_RELAXED, __HIP_MEMORY_SCOPE_AGENT);
}

__global__ __launch_bounds__(NTHR, 1) void xlstm_k(
    const float* __restrict__ x,
    const float* __restrict__ bi, const float* __restrict__ bf_,
    const float* __restrict__ bo, const float* __restrict__ bc,
    const float* __restrict__ be,
    float* __restrict__ out, float* __restrict__ ws)
{
    __shared__ unsigned short sA[16 * 776];  // 24.8 KB xh tile bf16 (row pad 8)
    __shared__ float zs[1024];               // gate z [4 gate][16 b][16 u]
    __shared__ float zel[16 * 68];           // ze [16 b][64 e] (pad 68)
    __shared__ float esm[16 * 68];           // e   [16 b][64]  (pad 68)
    __shared__ float sbe[64];                // be staged
    __shared__ uint4 chs[8][256];            // chist bf16: chs[q][tid] = slots 8q..8q+7

    unsigned* flags = (unsigned*)ws;
    unsigned* hbu = (unsigned*)(ws + HB_OFF);
    const unsigned short* BPU = (const unsigned short*)(ws + BP_OFF);
    const unsigned short* BPE = BPU + BPU_SH;

    const int tid = threadIdx.x, wg = blockIdx.x;
    const int bt = wg >> 5, r = wg & 31;
    const int b0 = bt << 4, u0 = r << 4;
    const int lane = tid & 63, w = tid >> 6;       // wave = gate index
    const int quad = lane >> 4, m16 = lane & 15;
    const unsigned short* aBase = sA + m16 * 776 + (quad << 3);
    unsigned* myflag = flags + (bt << 5) + r;
    unsigned* bflags = flags + (bt << 5);

    const int bb = tid >> 4, uu = tid & 15;
    const float bia_i = bi[u0 + uu], bia_f = bf_[u0 + uu];
    const float bia_o = bo[u0 + uu], bia_c = bc[u0 + uu];
    float* outp = out + (ull)((b0 + bb) * Tn) * 512 + u0 + uu;
    const float4* xg = (const float4*)x;

    if (tid < 64) sbe[tid] = be[tid];
    #pragma unroll
    for (int q = 0; q < 8; ++q) chs[q][tid] = make_uint4(0u, 0u, 0u, 0u);  // zero c-history

    // -------- preload ALL B fragments into registers (loop-invariant) --------
    const short8* Bg = (const short8*)BPU + (r * 4 + w) * 24 * 64 + lane;
    const short8* Be = (const short8*)BPE + w * 24 * 64 + lane;
    short8 Bfg[24], Bfe[24];
    #pragma unroll
    for (int i = 0; i < 24; ++i) { Bfg[i] = Bg[i << 6]; Bfe[i] = Be[i << 6]; }

    // initial x prefetch (t = 0)
    float4 xv[4];
    #pragma unroll
    for (int i2 = 0; i2 < 4; ++i2) {
        const int i = (i2 << 8) + tid;
        xv[i2] = xg[(((b0 + (i >> 6)) * Tn) << 6) + (i & 63)];
    }
    __syncthreads();

    for (int t = 0; t < Tn; ++t) {
        // -------- stage x_t -> sA (bf16), then prefetch x_{t+1} --------
        #pragma unroll
        for (int i2 = 0; i2 < 4; ++i2) {
            const int i = (i2 << 8) + tid;
            ushort4 o; o.x = f2bf(xv[i2].x); o.y = f2bf(xv[i2].y);
            o.z = f2bf(xv[i2].z); o.w = f2bf(xv[i2].w);
            *(ushort4*)(sA + (i >> 6) * 776 + ((i & 63) << 2)) = o;
        }
        if (t + 1 < Tn) {
            #pragma unroll
            for (int i2 = 0; i2 < 4; ++i2) {
                const int i = (i2 << 8) + tid;
                xv[i2] = xg[(((b0 + (i >> 6)) * Tn + t + 1) << 6) + (i & 63)];
            }
        }
        __syncthreads();

        // -------- x-part MFMAs (h-independent; B from registers) --------
        f32x4 ag = {0.f, 0.f, 0.f, 0.f}, ae = ag;
        #pragma unroll
        for (int kb = 0; kb < 8; ++kb) {
            const short8 a = *(const short8*)(aBase + (kb << 5));
            ag = __builtin_amdgcn_mfma_f32_16x16x32_bf16(a, Bfg[kb], ag, 0, 0, 0);
            ae = __builtin_amdgcn_mfma_f32_16x16x32_bf16(a, Bfe[kb], ae, 0, 0, 0);
        }

        // -------- single cross-wg wait: all 32 u-wgs of bt published h_t --------
        if (t) {
            if (tid < 32)
                while (ld_agent_u32(bflags + tid) < (unsigned)t)
                    __builtin_amdgcn_s_sleep(1);
            __syncthreads();
        }

        // -------- h agent load -> LDS --------
        ull hreg[8];
        const ull* hg = (const ull*)(hbu + ((t & 1) << 14)) + (b0 << 7);
        #pragma unroll
        for (int j = 0; j < 8; ++j) hreg[j] = ld_agent_u64(hg + (j << 8) + tid);
        #pragma unroll
        for (int j = 0; j < 8; ++j) {
            const int f = (j << 8) + tid;
            *(ull*)(sA + (f >> 7) * 776 + 256 + ((f & 127) << 2)) = hreg[j];
        }
        __syncthreads();

        // -------- h-part MFMAs (B from registers) --------
        #pragma unroll
        for (int kb = 8; kb < 24; ++kb) {
            const short8 a = *(const short8*)(aBase + (kb << 5));
            ag = __builtin_amdgcn_mfma_f32_16x16x32_bf16(a, Bfg[kb], ag, 0, 0, 0);
            ae = __builtin_amdgcn_mfma_f32_16x16x32_bf16(a, Bfe[kb], ae, 0, 0, 0);
        }

        // -------- exchange: gate z + ze into LDS --------
        #pragma unroll
        for (int i = 0; i < 4; ++i) {
            zs[(w << 8) + ((quad << 2) + i) * 16 + m16] = ag[i];
            zel[((quad << 2) + i) * 68 + (w << 4) + m16] = ae[i];
        }
        __syncthreads();

        // -------- local softmax over ze (16-lane groups per b) --------
        {
            const float* zb = zel + bb * 68;
            const int l = uu;
            float v0 = zb[l]      + sbe[l];
            float v1 = zb[l + 16] + sbe[l + 16];
            float v2 = zb[l + 32] + sbe[l + 32];
            float v3 = zb[l + 48] + sbe[l + 48];
            float mx = fmaxf(fmaxf(v0, v1), fmaxf(v2, v3));
            #pragma unroll
            for (int off = 8; off; off >>= 1) mx = fmaxf(mx, __shfl_xor(mx, off, 16));
            const float e0 = __expf(v0 - mx), e1 = __expf(v1 - mx);
            const float e2 = __expf(v2 - mx), e3 = __expf(v3 - mx);
            float ssum = e0 + e1 + e2 + e3;
            #pragma unroll
            for (int off = 8; off; off >>= 1) ssum += __shfl_xor(ssum, off, 16);
            const float inv = 1.0f / ssum;
            esm[bb * 68 + l]      = e0 * inv;
            esm[bb * 68 + l + 16] = e1 * inv;
            esm[bb * 68 + l + 32] = e2 * inv;
            esm[bb * 68 + l + 48] = e3 * inv;
        }
        __syncthreads();

        // -------- gates + 64-tap memory read + state update --------
        const float zi = zs[tid] + bia_i;
        const float zf = zs[256 + tid] + bia_f;
        const float zo = zs[512 + tid] + bia_o;
        const float zc = zs[768 + tid] + bia_c;
        float mc = 0.f;
        const float* eb = esm + bb * 68;
        const int jb = t + 63;                  // e index j = (t-1-slot) mod 64
        #pragma unroll
        for (int q = 0; q < 8; ++q) {           // slots 8q..8q+7 (bf16 in uint4)
            const uint4 v = chs[q][tid];
            const int s = q << 3;
            mc = fmaf(__uint_as_float(v.x << 16),         eb[(jb - s) & 63], mc);
            mc = fmaf(__uint_as_float(v.x & 0xFFFF0000u), eb[(jb - s - 1) & 63], mc);
            mc = fmaf(__uint_as_float(v.y << 16),         eb[(jb - s - 2) & 63], mc);
            mc = fmaf(__uint_as_float(v.y & 0xFFFF0000u), eb[(jb - s - 3) & 63], mc);
            mc = fmaf(__uint_as_float(v.z << 16),         eb[(jb - s - 4) & 63], mc);
            mc = fmaf(__uint_as_float(v.z & 0xFFFF0000u), eb[(jb - s - 5) & 63], mc);
            mc = fmaf(__uint_as_float(v.w << 16),         eb[(jb - s - 6) & 63], mc);
            mc = fmaf(__uint_as_float(v.w & 0xFFFF0000u), eb[(jb - s - 7) & 63], mc);
        }
        const float cc = sigmoidf_(zf) * mc + sigmoidf_(zi) * tanhf_(zc);
        const float hh = sigmoidf_(zo) * tanhf_(cc);
        ((unsigned short*)&chs[(t & 63) >> 3][tid])[t & 7] = f2bf(cc);  // newest c
        const float nh = __shfl_xor(hh, 1);
        if (!(tid & 1)) {                       // pack 2 u's -> u32 bf16 (agent)
            const unsigned v = (unsigned)f2bf(hh) | ((unsigned)f2bf(nh) << 16);
            st_agent_u32(hbu + (((t + 1) & 1) << 14) + ((b0 + bb) << 8)
                         + ((u0 + uu) >> 1), v);
        }
        // -------- publish: drain h stores, align wg, set own flag (no RMW) --------
        __builtin_amdgcn_s_waitcnt(0);
        __syncthreads();
        if (tid == 0) st_agent_u32(myflag, (unsigned)(t + 1));
        outp[t << 9] = hh;                      // out store AFTER publish (off-path)
    }
}

// ---------------- init: zero flags/h, pack bf16 MFMA-ordered weights ----------------
__global__ __launch_bounds__(NTHR) void init_k(
    const float* __restrict__ Wi, const float* __restrict__ Ui,
    const float* __restrict__ Wf, const float* __restrict__ Uf,
    const float* __restrict__ Wo, const float* __restrict__ Uo,
    const float* __restrict__ Wc, const float* __restrict__ Uc,
    const float* __restrict__ We, const float* __restrict__ Ue,
    float* __restrict__ ws)
{
    const int idx = blockIdx.x * NTHR + threadIdx.x;
    const int stride = gridDim.x * NTHR;
    unsigned* ctr = (unsigned*)ws;
    for (int i = idx; i < 512; i += stride) ctr[i] = 0u;
    unsigned* hbu = (unsigned*)(ws + HB_OFF);
    for (int i = idx; i < 32768; i += stride) hbu[i] = 0u;   // both h buffers = 0

    unsigned short* BPU = (unsigned short*)(ws + BP_OFF);
    unsigned short* BPE = BPU + BPU_SH;
    const float* Wg[4] = {Wi, Wf, Wo, Wc};
    const float* Ug[4] = {Ui, Uf, Uo, Uc};
    // BPU[((rr*4+w2)*24+kb)*64+lane][j] = bf16([W;U]_gate_w2[k=kb*32+(lane>>4)*8+j][rr*16+(lane&15)])
    for (int g = idx; g < 196608; g += stride) {
        const int lane = g & 63, rest = g >> 6;
        const int kb = rest % 24, rest2 = rest / 24;
        const int w2 = rest2 & 3, rr = rest2 >> 2;
        const int cs = (rr << 4) + (lane & 15);
        const int kbase = (kb << 5) + ((lane >> 4) << 3);
        #pragma unroll
        for (int j = 0; j < 8; ++j) {
            const int k = kbase + j;
            const float v = (k < 256) ? Wg[w2][(k << 9) + cs]
                                      : Ug[w2][((k - 256) << 9) + cs];
            BPU[(g << 3) + j] = f2bf(v);
        }
    }
    for (int g = idx; g < 6144; g += stride) {
        const int lane = g & 63, rest = g >> 6;
        const int kb = rest % 24, w2 = rest / 24;
        const int cs = (w2 << 4) + (lane & 15);
        const int kbase = (kb << 5) + ((lane >> 4) << 3);
        #pragma unroll
        for (int j = 0; j < 8; ++j) {
            const int k = kbase + j;
            const float v = (k < 256) ? We[(k << 6) + cs] : Ue[((k - 256) << 6) + cs];
            BPE[(g << 3) + j] = f2bf(v);
        }
    }
}

extern "C" void kernel_launch(void* const* d_in, const int* in_sizes, int n_in,
                              void* d_out, int out_size, void* d_ws, size_t ws_size,
                              hipStream_t stream) {
    const float* x  = (const float*)d_in[0];
    const float* Wi = (const float*)d_in[1];
    const float* Ui = (const float*)d_in[2];
    const float* bi = (const float*)d_in[3];
    const float* Wf = (const float*)d_in[4];
    const float* Uf = (const float*)d_in[5];
    const float* bf = (const float*)d_in[6];
    const float* Wo = (const float*)d_in[7];
    const float* Uo = (const float*)d_in[8];
    const float* bo = (const float*)d_in[9];
    const float* Wc = (const float*)d_in[10];
    const float* Uc = (const float*)d_in[11];
    const float* bc = (const float*)d_in[12];
    const float* We = (const float*)d_in[13];
    const float* Ue = (const float*)d_in[14];
    const float* be = (const float*)d_in[15];
    float* out = (float*)d_out;
    float* ws  = (float*)d_ws;

    init_k<<<512, NTHR, 0, stream>>>(Wi, Ui, Wf, Uf, Wo, Uo, Wc, Uc, We, Ue, ws);

    void* args[] = { &x, &bi, &bf, &bo, &bc, &be, &out, &ws };
    hipError_t e = hipLaunchCooperativeKernel((const void*)xlstm_k,
                                              dim3(GRID), dim3(NTHR), args, 0, stream);
    if (e != hipSuccess) {
        (void)hipGetLastError();   // 128 wgs co-reside trivially; plain launch fallback
        xlstm_k<<<GRID, NTHR, 0, stream>>>(x, bi, bf, bo, bc, be, out, ws);
    }
}